// Round 11
// baseline (309.249 us; speedup 1.0000x reference)
//
#include <hip/hip_runtime.h>
#include <stdint.h>

typedef unsigned short u16;
typedef u16   u16x4  __attribute__((ext_vector_type(4)));
typedef u16   u16x8  __attribute__((ext_vector_type(8)));
typedef __bf16 bf16x8 __attribute__((ext_vector_type(8)));
typedef float f32x4  __attribute__((ext_vector_type(4)));

typedef __attribute__((address_space(3))) u16 lds_u16;
typedef __attribute__((address_space(1))) const u16 glb_u16;

static __device__ __forceinline__ u16 f32_bf16(float f) {
    uint32_t u = __builtin_bit_cast(uint32_t, f);
    u += 0x7fffu + ((u >> 16) & 1u);          // round-to-nearest-even
    return (u16)(u >> 16);
}
static __device__ __forceinline__ u16x8 cvt8(f32x4 a, f32x4 b) {
    u16x8 v;
#pragma unroll
    for (int e = 0; e < 4; ++e) { v[e] = f32_bf16(a[e]); v[4 + e] = f32_bf16(b[e]); }
    return v;
}

// ---------------------------------------------------------------------------
// 0. dtype detect (verified R5-R10): flag=1 -> fp32 inputs AND fp32 output.
// ---------------------------------------------------------------------------
__global__ __launch_bounds__(256) void detect_k(const u16* __restrict__ X, uint32_t* flag) {
    __shared__ int cnt[256];
    int t = threadIdx.x;
    int c = 0;
#pragma unroll
    for (int i = 0; i < 4; ++i) {
        u16 v = X[t + 256 * i];
        int e = (v >> 7) & 0xFF;
        c += (e >= 0xC2) ? 1 : 0;
    }
    cnt[t] = c;
    __syncthreads();
    for (int s = 128; s > 0; s >>= 1) {
        if (t < s) cnt[t] += cnt[t + s];
        __syncthreads();
    }
    if (t == 0) *flag = (cnt[0] > 32) ? 1u : 0u;
}

// ---------------------------------------------------------------------------
// 0b. X pre-convert to bf16 (identity copy when flag=0).
// ---------------------------------------------------------------------------
struct XJob { const void* in; u16* out; int n; };

__global__ __launch_bounds__(256) void convert_x(XJob j0, XJob j1, const uint32_t* __restrict__ flag) {
    const XJob job = (blockIdx.y == 0) ? j0 : j1;
    const bool f32in = (*flag != 0u);
    const int stride = gridDim.x * 256 * 8;
    for (int i = ((int)blockIdx.x * 256 + (int)threadIdx.x) * 8; i < job.n; i += stride) {
        u16x8 v;
        if (f32in) {
            const float* p = (const float*)job.in + i;
            v = cvt8(*(const f32x4*)p, *(const f32x4*)(p + 4));
        } else {
            v = *(const u16x8*)((const u16*)job.in + i);
        }
        *(u16x8*)(job.out + i) = v;
    }
}

// ---------------------------------------------------------------------------
// 1. Weight convert+transpose, all 8 matrices in one dispatch.
// ---------------------------------------------------------------------------
struct WJob { const void* in; u16* out; };
struct WBatch8 { WJob j[8]; };

__global__ __launch_bounds__(256) void convert_w(WBatch8 args, const uint32_t* __restrict__ flag) {
    __shared__ u16 tile[64][72];
    const bool f32in = (*flag != 0u);
    const void* in = args.j[blockIdx.z].in;
    u16*       out = args.j[blockIdx.z].out;
    const int t  = threadIdx.x;
    const int r0 = blockIdx.y * 64, c0 = blockIdx.x * 64;
    const int lr = t >> 3, lc = (t & 7) * 8;
#pragma unroll
    for (int pass = 0; pass < 2; ++pass) {
        int r = lr + pass * 32;
        u16x8 v;
        if (f32in) {
            const float* p = (const float*)in + (size_t)(r0 + r) * 1024 + c0 + lc;
            v = cvt8(*(const f32x4*)p, *(const f32x4*)(p + 4));
        } else {
            v = *(const u16x8*)((const u16*)in + (size_t)(r0 + r) * 1024 + c0 + lc);
        }
#pragma unroll
        for (int e = 0; e < 8; ++e) tile[r][lc + e] = v[e];
    }
    __syncthreads();
#pragma unroll
    for (int pass = 0; pass < 2; ++pass) {
        int n = lr + pass * 32;
        u16x8 v;
#pragma unroll
        for (int e = 0; e < 8; ++e) v[e] = tile[lc + e][n];
        *(u16x8*)(out + (size_t)(c0 + n) * 1024 + r0 + lc) = v;
    }
}

// ---------------------------------------------------------------------------
// 2. MFMA GEMM, BK=64 (16 K-iters, half the barrier drains of BK=32).
//    Staging via global_load_lds width=16, source-side XOR swizzle
//    (8 chunks per 128B row). LDS 2x16 KB -> 5 blocks/CU.
// ---------------------------------------------------------------------------
struct GemmJob  { const u16* A; const u16* Bt; void* C; int M; int cF32able; int cOffElems; int vtNk; };
struct GemmBatch6 { GemmJob j[6]; };

__global__ __launch_bounds__(256) void gemm_bt(GemmBatch6 b, const uint32_t* __restrict__ flag) {
    const GemmJob job = b.j[blockIdx.z];
    const int K = 1024, N = 1024;
    const int m0 = blockIdx.y * 128;
    if (m0 >= job.M) return;
    const int n0 = blockIdx.x * 128;
    const bool cF = job.cF32able && (*flag != 0u);

    __shared__ u16 As[128 * 64];
    __shared__ u16 Bs[128 * 64];

    const int tid  = threadIdx.x;
    const int lane = tid & 63, wave = tid >> 6;
    const int quad = lane >> 4, l16 = lane & 15;
    const int wrow = wave >> 1, wcol = wave & 1;

    f32x4 acc[4][4];
#pragma unroll
    for (int i = 0; i < 4; ++i)
#pragma unroll
        for (int j = 0; j < 4; ++j) acc[i][j] = (f32x4){0.f, 0.f, 0.f, 0.f};

    for (int k0 = 0; k0 < K; k0 += 64) {
        __syncthreads();                       // prev iter LDS reads done
#pragma unroll
        for (int i = 0; i < 4; ++i) {
            int id = tid + 256 * i;            // 1024 chunks of 16B per operand
            int row = id >> 3, slot = id & 7;
            int src = (slot ^ (row & 7)) * 8;  // source-side swizzle (8 chunks/row)
            __builtin_amdgcn_global_load_lds(
                (glb_u16*)(job.A + (size_t)(m0 + row) * K + k0 + src),
                (lds_u16*)(As + (size_t)id * 8), 16, 0, 0);
            __builtin_amdgcn_global_load_lds(
                (glb_u16*)(job.Bt + (size_t)(n0 + row) * K + k0 + src),
                (lds_u16*)(Bs + (size_t)id * 8), 16, 0, 0);
        }
        __syncthreads();                       // staged (vmcnt drained at barrier)

#pragma unroll
        for (int kc2 = 0; kc2 < 2; ++kc2) {
            bf16x8 af[4], bfb[4];
#pragma unroll
            for (int i = 0; i < 4; ++i) {
                int r  = wrow * 64 + i * 16 + l16;
                af[i]  = *(const bf16x8*)(As + r * 64 + (((kc2 * 4 + quad) ^ (r & 7)) * 8));
                int rn = wcol * 64 + i * 16 + l16;
                bfb[i] = *(const bf16x8*)(Bs + rn * 64 + (((kc2 * 4 + quad) ^ (rn & 7)) * 8));
            }
#pragma unroll
            for (int i = 0; i < 4; ++i)
#pragma unroll
                for (int j = 0; j < 4; ++j)
                    acc[i][j] = __builtin_amdgcn_mfma_f32_16x16x32_bf16(af[i], bfb[j], acc[i][j], 0, 0, 0);
        }
    }

    if (job.vtNk > 0) {
        u16* VT = (u16*)job.C;
        const int Nk2 = job.vtNk;
#pragma unroll
        for (int i = 0; i < 4; ++i)
#pragma unroll
            for (int j = 0; j < 4; ++j) {
                int n   = n0 + wcol * 64 + j * 16 + l16;
                int hh  = n >> 6, dd = n & 63;
                int key = m0 + wrow * 64 + i * 16 + quad * 4;
                u16x4 vv;
#pragma unroll
                for (int r = 0; r < 4; ++r) vv[r] = f32_bf16(acc[i][j][r]);
                *(u16x4*)(VT + (size_t)hh * 64 * Nk2 + (size_t)dd * Nk2 + key) = vv;
            }
    } else if (cF) {
        float* C = (float*)job.C + job.cOffElems;
#pragma unroll
        for (int i = 0; i < 4; ++i)
#pragma unroll
            for (int j = 0; j < 4; ++j)
#pragma unroll
                for (int r = 0; r < 4; ++r) {
                    int gr = m0 + wrow * 64 + i * 16 + quad * 4 + r;
                    int gc = n0 + wcol * 64 + j * 16 + l16;
                    C[(size_t)gr * N + gc] = acc[i][j][r];
                }
    } else {
        u16* C = (u16*)job.C + job.cOffElems;
#pragma unroll
        for (int i = 0; i < 4; ++i)
#pragma unroll
            for (int j = 0; j < 4; ++j)
#pragma unroll
                for (int r = 0; r < 4; ++r) {
                    int gr = m0 + wrow * 64 + i * 16 + quad * 4 + r;
                    int gc = n0 + wcol * 64 + j * 16 + l16;
                    C[(size_t)gr * N + gc] = f32_bf16(acc[i][j][r]);
                }
    }
}

// ---------------------------------------------------------------------------
// 3. Fused MFMA attention v5 — BARRIER-FREE main loop. Each wave owns a
//    private 32-key K strip (32x64, XOR chunks) + V strip (64x32, XOR chunks)
//    in LDS, register-prefetched one tile ahead. No cross-wave data flow
//    until the final combine -> zero __syncthreads in the K-loop; waves
//    free-run instead of convoying on the shared LDS pipe.
//    LDS: 4x8KB strips + 4x2.5KB P + Lb = 43.3 KB -> 3 blocks/CU.
// ---------------------------------------------------------------------------
struct AttnDir { const u16* Q; const u16* K; const u16* VT; u16* ctxT; int Nq; int Nk; int nBlk; };

__global__ __launch_bounds__(256, 3) void attn_k(AttnDir d0, AttnDir d1) {
    const int D = 1024;
    int b = blockIdx.x;
    const AttnDir dd = (b < d0.nBlk) ? d0 : d1;
    if (blockIdx.x >= (unsigned)d0.nBlk) b -= d0.nBlk;
    const int h  = b & 15;
    const int q0 = (b >> 4) * 64;
    const int Nq = dd.Nq, Nk = dd.Nk;
    const u16* __restrict__ Qp  = dd.Q;
    const u16* __restrict__ Kp  = dd.K;
    const u16* __restrict__ VTp = dd.VT;

    const int tid  = threadIdx.x;
    const int lane = tid & 63, w = tid >> 6;
    const int quad = lane >> 4, l16 = lane & 15;
    const int qhalf = w & 1, khalf = w >> 1;
    const int halfN = Nk >> 1;

    __shared__ u16 smem[21632];       // 43264 B
    u16* Ks = smem + w * 4096;        // private [32 keys][64 d]
    u16* Vs = smem + w * 4096 + 2048; // private [64 d][32 keys]
    u16* Pb = smem + 16384;           // 4 x [32 q][40]
    float* Lb = (float*)(smem + 21504);

    bf16x8 aq[2][2];
#pragma unroll
    for (int ms = 0; ms < 2; ++ms)
#pragma unroll
        for (int kc = 0; kc < 2; ++kc) {
            int q = q0 + qhalf * 32 + ms * 16 + l16;
            aq[ms][kc] = *(const bf16x8*)(Qp + (size_t)q * D + h * 64 + kc * 32 + quad * 8);
        }

    f32x4 o[2][4];
#pragma unroll
    for (int ms = 0; ms < 2; ++ms)
#pragma unroll
        for (int nj = 0; nj < 4; ++nj) o[ms][nj] = (f32x4){0.f, 0.f, 0.f, 0.f};
    float rs[2][4] = {};
    const float sc = 0.125f;
    u16* P = Pb + w * 1280;
    const size_t vtBase = (size_t)h * 64 * Nk;
    const int gkBase0 = khalf * halfN;

    // per-lane staging coords (4 chunks each for K and V)
    int krow[4], ksrc[4], vd[4], vsrc[4];
#pragma unroll
    for (int i = 0; i < 4; ++i) {
        int id = i * 64 + lane;
        krow[i] = id >> 3;                       // 0..31 key
        ksrc[i] = ((id & 7) ^ (krow[i] & 7)) * 8;   // source d-chunk (swizzled)
        vd[i]   = id >> 2;                       // 0..63 d
        vsrc[i] = ((id & 3) ^ ((vd[i] >> 1) & 3)) * 8;  // source key-chunk
    }

    u16x8 kr[4], vr[4];
#pragma unroll
    for (int i = 0; i < 4; ++i) {   // prefetch tile 0
        kr[i] = *(const u16x8*)(Kp + (size_t)(gkBase0 + krow[i]) * D + h * 64 + ksrc[i]);
        vr[i] = *(const u16x8*)(VTp + vtBase + (size_t)vd[i] * Nk + gkBase0 + vsrc[i]);
    }

    for (int k0 = 0; k0 < halfN; k0 += 32) {
        // stage own strip (compiler waits vmcnt for kr/vr; no block barrier)
#pragma unroll
        for (int i = 0; i < 4; ++i) {
            int id = i * 64 + lane;
            *(u16x8*)(Ks + id * 8) = kr[i];
            *(u16x8*)(Vs + id * 8) = vr[i];
        }
        // prefetch next tile (WAR-safe: LDS writes above consumed the regs)
        {
            int kn = (k0 + 32 < halfN) ? (k0 + 32) : 0;
            int gkb = gkBase0 + kn;
#pragma unroll
            for (int i = 0; i < 4; ++i) {
                kr[i] = *(const u16x8*)(Kp + (size_t)(gkb + krow[i]) * D + h * 64 + ksrc[i]);
                vr[i] = *(const u16x8*)(VTp + vtBase + (size_t)vd[i] * Nk + gkb + vsrc[i]);
            }
        }

        // S = Q K^T over own 32-key strip (lgkmcnt wait auto-inserted)
        f32x4 s[2][2];
#pragma unroll
        for (int ms = 0; ms < 2; ++ms)
#pragma unroll
            for (int kn = 0; kn < 2; ++kn) s[ms][kn] = (f32x4){0.f, 0.f, 0.f, 0.f};
#pragma unroll
        for (int kn = 0; kn < 2; ++kn)
#pragma unroll
            for (int kc = 0; kc < 2; ++kc) {
                int keyr = kn * 16 + l16;        // local key 0..31
                int phys = ((kc * 4 + quad) ^ (keyr & 7)) * 8;
                bf16x8 bk = *(const bf16x8*)(Ks + keyr * 64 + phys);
#pragma unroll
                for (int ms = 0; ms < 2; ++ms)
                    s[ms][kn] = __builtin_amdgcn_mfma_f32_16x16x32_bf16(aq[ms][kc], bk, s[ms][kn], 0, 0, 0);
            }

        // exp + rowsum + P -> LDS (per-wave buffer, no sync)
#pragma unroll
        for (int ms = 0; ms < 2; ++ms)
#pragma unroll
            for (int kn = 0; kn < 2; ++kn) {
                int key = kn * 16 + l16;
#pragma unroll
                for (int r = 0; r < 4; ++r) {
                    float p = __expf(s[ms][kn][r] * sc);
                    rs[ms][r] += p;
                    int ql = ms * 16 + quad * 4 + r;
                    P[ql * 40 + key] = f32_bf16(p);
                }
            }

        bf16x8 pa[2];
#pragma unroll
        for (int ms = 0; ms < 2; ++ms)
            pa[ms] = *(const bf16x8*)(P + (ms * 16 + l16) * 40 + quad * 8);

#pragma unroll
        for (int nj = 0; nj < 4; ++nj) {
            int d = nj * 16 + l16;
            int physv = (quad ^ ((d >> 1) & 3)) * 8;
            bf16x8 bv = *(const bf16x8*)(Vs + d * 32 + physv);
#pragma unroll
            for (int ms = 0; ms < 2; ++ms)
                o[ms][nj] = __builtin_amdgcn_mfma_f32_16x16x32_bf16(pa[ms], bv, o[ms][nj], 0, 0, 0);
        }
    }

    // reduce row-sums across the 16 key-lanes
#pragma unroll
    for (int ms = 0; ms < 2; ++ms)
#pragma unroll
        for (int r = 0; r < 4; ++r) {
            float v = rs[ms][r];
            v += __shfl_xor(v, 1, 64);
            v += __shfl_xor(v, 2, 64);
            v += __shfl_xor(v, 4, 64);
            v += __shfl_xor(v, 8, 64);
            rs[ms][r] = v;
        }

    // cross-khalf combine (additive partials)
    __syncthreads();                  // all waves done with their strips
    float* Cb = (float*)smem;         // [64 q][64 d] fp32 = 16 KB over strips
    if (khalf == 1) {
#pragma unroll
        for (int ms = 0; ms < 2; ++ms)
#pragma unroll
            for (int nj = 0; nj < 4; ++nj)
#pragma unroll
                for (int r = 0; r < 4; ++r)
                    Cb[(qhalf * 32 + ms * 16 + quad * 4 + r) * 64 + nj * 16 + l16] = o[ms][nj][r];
        if (l16 == 0)
#pragma unroll
            for (int ms = 0; ms < 2; ++ms)
#pragma unroll
                for (int r = 0; r < 4; ++r)
                    Lb[qhalf * 32 + ms * 16 + quad * 4 + r] = rs[ms][r];
    }
    __syncthreads();
    if (khalf == 0) {
        float inv[2][4];
#pragma unroll
        for (int ms = 0; ms < 2; ++ms)
#pragma unroll
            for (int r = 0; r < 4; ++r)
                inv[ms][r] = 1.0f / (rs[ms][r] + Lb[qhalf * 32 + ms * 16 + quad * 4 + r]);

        u16* R = Pb + w * 2560;       // [64 d][40] u16
#pragma unroll
        for (int ms = 0; ms < 2; ++ms)
#pragma unroll
            for (int nj = 0; nj < 4; ++nj)
#pragma unroll
                for (int r = 0; r < 4; ++r) {
                    int d  = nj * 16 + l16;
                    int ql = ms * 16 + quad * 4 + r;
                    float v = o[ms][nj][r] + Cb[(qhalf * 32 + ql) * 64 + nj * 16 + l16];
                    R[d * 40 + ql] = f32_bf16(v * inv[ms][r]);
                }
#pragma unroll
        for (int i = 0; i < 4; ++i) {
            int cid = lane + 64 * i;
            int d = cid >> 2, c = cid & 3;
            u16x8 v = *(const u16x8*)(R + d * 40 + c * 8);
            *(u16x8*)(dd.ctxT + (size_t)h * 64 * Nq + (size_t)d * Nq + q0 + qhalf * 32 + c * 8) = v;
        }
    }
}

// ---------------------------------------------------------------------------
// launch — identical plan to R9/R10 (ws peak 40 MB; d_out u16 staging).
// ---------------------------------------------------------------------------
extern "C" void kernel_launch(void* const* d_in, const int* in_sizes, int n_in,
                              void* d_out, int out_size, void* d_ws, size_t ws_size,
                              hipStream_t stream) {
    u16* ws = (u16*)d_ws;
    uint32_t* flag = (uint32_t*)ws;
    u16* A = ws + 64;
    const size_t M1 = 1024ull * 1024;

    u16* W8   = A;              // [0,8M)  : 8 weightsT; [0,3M) later ctx1
    u16* Kd1  = A + 8 * M1;     // [8M,10M) : X@WK natural
    u16* VT   = A + 10 * M1;    // [10M,12M): VT[16][64][2048]
    u16* K1d  = A + 12 * M1;    // [12M,15M): X1@WK1 natural
    u16* VT1  = A + 15 * M1;    // [15M,18M): VT1[16][64][3072]
    u16* ctx2 = A + 18 * M1;    // [18M,20M)

    u16* outw = (u16*)d_out;
    u16* Q1s  = outw;           // [0,3M)  X1@WQ1 (bf16 scratch in d_out)
    u16* Qs   = outw + 3 * M1;  // [3M,5M) X@WQ
    u16* Xb   = outw + 5 * M1;  // [5M,7M)  X as bf16
    u16* X1b  = outw + 7 * M1;  // [7M,10M) X1 as bf16

    u16* ctx1 = W8;
    u16* WfcT = W8 + 6 * M1;

    detect_k<<<dim3(1), dim3(256), 0, stream>>>((const u16*)d_in[0], flag);

    XJob xj0 = {d_in[0], Xb,  2048 * 1024};
    XJob xj1 = {d_in[1], X1b, 3072 * 1024};
    convert_x<<<dim3(128, 2), dim3(256), 0, stream>>>(xj0, xj1, flag);

    WBatch8 wb;
    for (int i = 0; i < 8; ++i) { wb.j[i].in = d_in[2 + i]; wb.j[i].out = W8 + (size_t)i * M1; }
    convert_w<<<dim3(16, 16, 8), dim3(256), 0, stream>>>(wb, flag);

    GemmBatch6 gp;
    gp.j[0] = (GemmJob){Xb,  W8,          Qs,  2048, 0, 0, 0};
    gp.j[1] = (GemmJob){Xb,  W8 + M1,     Kd1, 2048, 0, 0, 0};
    gp.j[2] = (GemmJob){Xb,  W8 + 2 * M1, VT,  2048, 0, 0, 2048};
    gp.j[3] = (GemmJob){X1b, W8 + 3 * M1, Q1s, 3072, 0, 0, 0};
    gp.j[4] = (GemmJob){X1b, W8 + 4 * M1, K1d, 3072, 0, 0, 0};
    gp.j[5] = (GemmJob){X1b, W8 + 5 * M1, VT1, 3072, 0, 0, 3072};
    gemm_bt<<<dim3(8, 24, 6), dim3(256), 0, stream>>>(gp, flag);

    AttnDir a0 = {Q1s, Kd1, VT,  ctx1, 3072, 2048, 768};
    AttnDir a1 = {Qs,  K1d, VT1, ctx2, 2048, 3072, 512};
    attn_k<<<dim3(1280), dim3(256), 0, stream>>>(a0, a1);

    GemmBatch6 gf;
    gf.j[0] = (GemmJob){ctx1, WfcT,      d_out, 3072, 1, 0,               0};
    gf.j[1] = (GemmJob){ctx2, WfcT + M1, d_out, 2048, 1, 3 * 1024 * 1024, 0};
    gf.j[2] = gf.j[0]; gf.j[3] = gf.j[0]; gf.j[4] = gf.j[0]; gf.j[5] = gf.j[0];
    gemm_bt<<<dim3(8, 24, 2), dim3(256), 0, stream>>>(gf, flag);
}

// Round 12
// 291.344 us; speedup vs baseline: 1.0615x; 1.0615x over previous
//
#include <hip/hip_runtime.h>
#include <stdint.h>

typedef unsigned short u16;
typedef unsigned int u32;
typedef u16   u16x4  __attribute__((ext_vector_type(4)));
typedef u16   u16x8  __attribute__((ext_vector_type(8)));
typedef short s16x4  __attribute__((ext_vector_type(4)));
typedef __bf16 bf16x4 __attribute__((ext_vector_type(4)));
typedef __bf16 bf16x8 __attribute__((ext_vector_type(8)));
typedef float f32x4  __attribute__((ext_vector_type(4)));
typedef u32   u32x2  __attribute__((ext_vector_type(2)));

typedef __attribute__((address_space(3))) u16 lds_u16;
typedef __attribute__((address_space(1))) const u16 glb_u16;

static __device__ __forceinline__ u16 f32_bf16(float f) {
    uint32_t u = __builtin_bit_cast(uint32_t, f);
    u += 0x7fffu + ((u >> 16) & 1u);          // round-to-nearest-even
    return (u16)(u >> 16);
}
static __device__ __forceinline__ u32 pack_bf16(float a, float b) {
    return (u32)f32_bf16(a) | ((u32)f32_bf16(b) << 16);
}
static __device__ __forceinline__ u16x8 cvt8(f32x4 a, f32x4 b) {
    u16x8 v;
#pragma unroll
    for (int e = 0; e < 4; ++e) { v[e] = f32_bf16(a[e]); v[4 + e] = f32_bf16(b[e]); }
    return v;
}

// K=16 bf16 MFMA with builtin-name fallback chain
static __device__ __forceinline__ f32x4 mfma16(u32x2 a, u32x2 b, f32x4 c) {
#if __has_builtin(__builtin_amdgcn_mfma_f32_16x16x16_bf16)
    return __builtin_amdgcn_mfma_f32_16x16x16_bf16(
        __builtin_bit_cast(bf16x4, a), __builtin_bit_cast(bf16x4, b), c, 0, 0, 0);
#elif __has_builtin(__builtin_amdgcn_mfma_f32_16x16x16bf16_1k)
    return __builtin_amdgcn_mfma_f32_16x16x16bf16_1k(
        __builtin_bit_cast(s16x4, a), __builtin_bit_cast(s16x4, b), c, 0, 0, 0);
#else
    f32x4 d;
    asm volatile("v_mfma_f32_16x16x16_bf16 %0, %1, %2, %3"
                 : "=v"(d) : "v"(a), "v"(b), "v"(c));
    return d;
#endif
}

// ---------------------------------------------------------------------------
// 0. dtype detect (verified R5-R11): flag=1 -> fp32 inputs AND fp32 output.
// ---------------------------------------------------------------------------
__global__ __launch_bounds__(256) void detect_k(const u16* __restrict__ X, uint32_t* flag) {
    __shared__ int cnt[256];
    int t = threadIdx.x;
    int c = 0;
#pragma unroll
    for (int i = 0; i < 4; ++i) {
        u16 v = X[t + 256 * i];
        int e = (v >> 7) & 0xFF;
        c += (e >= 0xC2) ? 1 : 0;
    }
    cnt[t] = c;
    __syncthreads();
    for (int s = 128; s > 0; s >>= 1) {
        if (t < s) cnt[t] += cnt[t + s];
        __syncthreads();
    }
    if (t == 0) *flag = (cnt[0] > 32) ? 1u : 0u;
}

// ---------------------------------------------------------------------------
// 0b. X pre-convert to bf16 (identity copy when flag=0).
// ---------------------------------------------------------------------------
struct XJob { const void* in; u16* out; int n; };

__global__ __launch_bounds__(256) void convert_x(XJob j0, XJob j1, const uint32_t* __restrict__ flag) {
    const XJob job = (blockIdx.y == 0) ? j0 : j1;
    const bool f32in = (*flag != 0u);
    const int stride = gridDim.x * 256 * 8;
    for (int i = ((int)blockIdx.x * 256 + (int)threadIdx.x) * 8; i < job.n; i += stride) {
        u16x8 v;
        if (f32in) {
            const float* p = (const float*)job.in + i;
            v = cvt8(*(const f32x4*)p, *(const f32x4*)(p + 4));
        } else {
            v = *(const u16x8*)((const u16*)job.in + i);
        }
        *(u16x8*)(job.out + i) = v;
    }
}

// ---------------------------------------------------------------------------
// 1. Weight convert+transpose, all 8 matrices in one dispatch.
// ---------------------------------------------------------------------------
struct WJob { const void* in; u16* out; };
struct WBatch8 { WJob j[8]; };

__global__ __launch_bounds__(256) void convert_w(WBatch8 args, const uint32_t* __restrict__ flag) {
    __shared__ u16 tile[64][72];
    const bool f32in = (*flag != 0u);
    const void* in = args.j[blockIdx.z].in;
    u16*       out = args.j[blockIdx.z].out;
    const int t  = threadIdx.x;
    const int r0 = blockIdx.y * 64, c0 = blockIdx.x * 64;
    const int lr = t >> 3, lc = (t & 7) * 8;
#pragma unroll
    for (int pass = 0; pass < 2; ++pass) {
        int r = lr + pass * 32;
        u16x8 v;
        if (f32in) {
            const float* p = (const float*)in + (size_t)(r0 + r) * 1024 + c0 + lc;
            v = cvt8(*(const f32x4*)p, *(const f32x4*)(p + 4));
        } else {
            v = *(const u16x8*)((const u16*)in + (size_t)(r0 + r) * 1024 + c0 + lc);
        }
#pragma unroll
        for (int e = 0; e < 8; ++e) tile[r][lc + e] = v[e];
    }
    __syncthreads();
#pragma unroll
    for (int pass = 0; pass < 2; ++pass) {
        int n = lr + pass * 32;
        u16x8 v;
#pragma unroll
        for (int e = 0; e < 8; ++e) v[e] = tile[lc + e][n];
        *(u16x8*)(out + (size_t)(c0 + n) * 1024 + r0 + lc) = v;
    }
}

// ---------------------------------------------------------------------------
// 2. MFMA GEMM, BK=64, global_load_lds staging (R11, verified).
// ---------------------------------------------------------------------------
struct GemmJob  { const u16* A; const u16* Bt; void* C; int M; int cF32able; int cOffElems; int vtNk; };
struct GemmBatch6 { GemmJob j[6]; };

__global__ __launch_bounds__(256) void gemm_bt(GemmBatch6 b, const uint32_t* __restrict__ flag) {
    const GemmJob job = b.j[blockIdx.z];
    const int K = 1024, N = 1024;
    const int m0 = blockIdx.y * 128;
    if (m0 >= job.M) return;
    const int n0 = blockIdx.x * 128;
    const bool cF = job.cF32able && (*flag != 0u);

    __shared__ u16 As[128 * 64];
    __shared__ u16 Bs[128 * 64];

    const int tid  = threadIdx.x;
    const int lane = tid & 63, wave = tid >> 6;
    const int quad = lane >> 4, l16 = lane & 15;
    const int wrow = wave >> 1, wcol = wave & 1;

    f32x4 acc[4][4];
#pragma unroll
    for (int i = 0; i < 4; ++i)
#pragma unroll
        for (int j = 0; j < 4; ++j) acc[i][j] = (f32x4){0.f, 0.f, 0.f, 0.f};

    for (int k0 = 0; k0 < K; k0 += 64) {
        __syncthreads();
#pragma unroll
        for (int i = 0; i < 4; ++i) {
            int id = tid + 256 * i;
            int row = id >> 3, slot = id & 7;
            int src = (slot ^ (row & 7)) * 8;
            __builtin_amdgcn_global_load_lds(
                (glb_u16*)(job.A + (size_t)(m0 + row) * K + k0 + src),
                (lds_u16*)(As + (size_t)id * 8), 16, 0, 0);
            __builtin_amdgcn_global_load_lds(
                (glb_u16*)(job.Bt + (size_t)(n0 + row) * K + k0 + src),
                (lds_u16*)(Bs + (size_t)id * 8), 16, 0, 0);
        }
        __syncthreads();

#pragma unroll
        for (int kc2 = 0; kc2 < 2; ++kc2) {
            bf16x8 af[4], bfb[4];
#pragma unroll
            for (int i = 0; i < 4; ++i) {
                int r  = wrow * 64 + i * 16 + l16;
                af[i]  = *(const bf16x8*)(As + r * 64 + (((kc2 * 4 + quad) ^ (r & 7)) * 8));
                int rn = wcol * 64 + i * 16 + l16;
                bfb[i] = *(const bf16x8*)(Bs + rn * 64 + (((kc2 * 4 + quad) ^ (rn & 7)) * 8));
            }
#pragma unroll
            for (int i = 0; i < 4; ++i)
#pragma unroll
                for (int j = 0; j < 4; ++j)
                    acc[i][j] = __builtin_amdgcn_mfma_f32_16x16x32_bf16(af[i], bfb[j], acc[i][j], 0, 0, 0);
        }
    }

    if (job.vtNk > 0) {
        u16* VT = (u16*)job.C;
        const int Nk2 = job.vtNk;
#pragma unroll
        for (int i = 0; i < 4; ++i)
#pragma unroll
            for (int j = 0; j < 4; ++j) {
                int n   = n0 + wcol * 64 + j * 16 + l16;
                int hh  = n >> 6, dd = n & 63;
                int key = m0 + wrow * 64 + i * 16 + quad * 4;
                u16x4 vv;
#pragma unroll
                for (int r = 0; r < 4; ++r) vv[r] = f32_bf16(acc[i][j][r]);
                *(u16x4*)(VT + (size_t)hh * 64 * Nk2 + (size_t)dd * Nk2 + key) = vv;
            }
    } else if (cF) {
        float* C = (float*)job.C + job.cOffElems;
#pragma unroll
        for (int i = 0; i < 4; ++i)
#pragma unroll
            for (int j = 0; j < 4; ++j)
#pragma unroll
                for (int r = 0; r < 4; ++r) {
                    int gr = m0 + wrow * 64 + i * 16 + quad * 4 + r;
                    int gc = n0 + wcol * 64 + j * 16 + l16;
                    C[(size_t)gr * N + gc] = acc[i][j][r];
                }
    } else {
        u16* C = (u16*)job.C + job.cOffElems;
#pragma unroll
        for (int i = 0; i < 4; ++i)
#pragma unroll
            for (int j = 0; j < 4; ++j)
#pragma unroll
                for (int r = 0; r < 4; ++r) {
                    int gr = m0 + wrow * 64 + i * 16 + quad * 4 + r;
                    int gc = n0 + wcol * 64 + j * 16 + l16;
                    C[(size_t)gr * N + gc] = f32_bf16(acc[i][j][r]);
                }
    }
}

// ---------------------------------------------------------------------------
// 3. Fused MFMA attention v6 — transposed-S pipeline, NO P LDS round-trip.
//    S^T = mfma(K_frag, Q_frag) (operand-symmetric swap); exp'd S^T C-frag
//    (reg r = key quad*4+r, lane = q) IS the B-operand of mfma 16x16x16, so
//    PV = mfma16(V^T_frag, packed P, o) directly. Output lands as O^T
//    (row=d, col=q) matching ctxT[h][d][q] stores. Private per-wave K/V
//    strips (barrier-free loop, register prefetch). LDS 36.3 KB -> 4 blk/CU.
//    Longest jobs (dir2, 48 iters) launch first.
// ---------------------------------------------------------------------------
struct AttnDir { const u16* Q; const u16* K; const u16* VT; u16* ctxT; int Nq; int Nk; int nBlk; };

__global__ __launch_bounds__(256, 4) void attn_k(AttnDir d0, AttnDir d1) {
    const int D = 1024;
    int b = blockIdx.x;
    const AttnDir dd = (b < d0.nBlk) ? d0 : d1;
    if (blockIdx.x >= (unsigned)d0.nBlk) b -= d0.nBlk;
    const int h  = b & 15;
    const int q0 = (b >> 4) * 64;
    const int Nq = dd.Nq, Nk = dd.Nk;
    const u16* __restrict__ Qp  = dd.Q;
    const u16* __restrict__ Kp  = dd.K;
    const u16* __restrict__ VTp = dd.VT;

    const int tid  = threadIdx.x;
    const int lane = tid & 63, w = tid >> 6;
    const int quad = lane >> 4, l16 = lane & 15;
    const int qhalf = w & 1, khalf = w >> 1;
    const int halfN = Nk >> 1;

    __shared__ u16 smem[18560];       // 37120 B: 4 x (Ks 2048 + Vs 2560) + Lb
    u16* Ks = smem + w * 4608;        // private [32 keys][64 d], XOR chunks
    u16* Vs = Ks + 2048;              // private [64 d][40 pad] keys linear
    float* Lb = (float*)(smem + 18432);

    bf16x8 aq[2][2];                  // Q fragments (serve as B operands)
#pragma unroll
    for (int ms = 0; ms < 2; ++ms)
#pragma unroll
        for (int kc = 0; kc < 2; ++kc) {
            int q = q0 + qhalf * 32 + ms * 16 + l16;
            aq[ms][kc] = *(const bf16x8*)(Qp + (size_t)q * D + h * 64 + kc * 32 + quad * 8);
        }

    f32x4 o[2][4];                    // O^T accumulators [ms][nj]
#pragma unroll
    for (int ms = 0; ms < 2; ++ms)
#pragma unroll
        for (int nj = 0; nj < 4; ++nj) o[ms][nj] = (f32x4){0.f, 0.f, 0.f, 0.f};
    float rs[2] = {0.f, 0.f};         // per-lane (q=l16) partial row-sums
    const float sc = 0.125f;
    const size_t vtBase = (size_t)h * 64 * Nk;
    const int gkBase0 = khalf * halfN;

    // staging coords: K 256 chunks (32 rows x 8), V 256 chunks (64 d x 4)
    int krow[4], ksrc[4], vd[4], vc[4];
#pragma unroll
    for (int i = 0; i < 4; ++i) {
        int id = i * 64 + lane;
        krow[i] = id >> 3;
        ksrc[i] = ((id & 7) ^ (krow[i] & 7)) * 8;
        vd[i]   = id >> 2;
        vc[i]   = id & 3;
    }

    u16x8 kr[4], vr[4];
#pragma unroll
    for (int i = 0; i < 4; ++i) {     // prefetch tile 0
        kr[i] = *(const u16x8*)(Kp + (size_t)(gkBase0 + krow[i]) * D + h * 64 + ksrc[i]);
        vr[i] = *(const u16x8*)(VTp + vtBase + (size_t)vd[i] * Nk + gkBase0 + vc[i] * 8);
    }

    for (int k0 = 0; k0 < halfN; k0 += 32) {
        // stage own strips (no block barrier)
#pragma unroll
        for (int i = 0; i < 4; ++i) {
            *(u16x8*)(Ks + (i * 64 + lane) * 8) = kr[i];
            *(u16x8*)(Vs + vd[i] * 40 + vc[i] * 8) = vr[i];
        }
        // prefetch next tile
        {
            int kn = (k0 + 32 < halfN) ? (k0 + 32) : 0;
            int gkb = gkBase0 + kn;
#pragma unroll
            for (int i = 0; i < 4; ++i) {
                kr[i] = *(const u16x8*)(Kp + (size_t)(gkb + krow[i]) * D + h * 64 + ksrc[i]);
                vr[i] = *(const u16x8*)(VTp + vtBase + (size_t)vd[i] * Nk + gkb + vc[i] * 8);
            }
        }

        // S^T = K Q^T : A = K-frag (m=key), B = Q-frag (n=q)
        f32x4 s[2][2];
#pragma unroll
        for (int ms = 0; ms < 2; ++ms)
#pragma unroll
            for (int kn = 0; kn < 2; ++kn) s[ms][kn] = (f32x4){0.f, 0.f, 0.f, 0.f};
#pragma unroll
        for (int kn = 0; kn < 2; ++kn)
#pragma unroll
            for (int kc = 0; kc < 2; ++kc) {
                int keyr = kn * 16 + l16;
                int phys = ((kc * 4 + quad) ^ (keyr & 7)) * 8;
                bf16x8 ak = *(const bf16x8*)(Ks + keyr * 64 + phys);
#pragma unroll
                for (int ms = 0; ms < 2; ++ms)
                    s[ms][kn] = __builtin_amdgcn_mfma_f32_16x16x32_bf16(ak, aq[ms][kc], s[ms][kn], 0, 0, 0);
            }

        // exp + rowsum + pack: C-frag (key=quad*4+r) -> B-operand of mfma16
        u32x2 pb[2][2];
#pragma unroll
        for (int ms = 0; ms < 2; ++ms)
#pragma unroll
            for (int kn = 0; kn < 2; ++kn) {
                float p0 = __expf(s[ms][kn][0] * sc);
                float p1 = __expf(s[ms][kn][1] * sc);
                float p2 = __expf(s[ms][kn][2] * sc);
                float p3 = __expf(s[ms][kn][3] * sc);
                rs[ms] += (p0 + p1) + (p2 + p3);
                pb[ms][kn][0] = pack_bf16(p0, p1);
                pb[ms][kn][1] = pack_bf16(p2, p3);
            }

        // PV: O^T += V^T_frag * P  (A: m=d lane=l16, k=key quad*4+j)
#pragma unroll
        for (int nj = 0; nj < 4; ++nj) {
            int d = nj * 16 + l16;
#pragma unroll
            for (int kn = 0; kn < 2; ++kn) {
                u32x2 va = *(const u32x2*)(Vs + d * 40 + kn * 16 + quad * 4);
#pragma unroll
                for (int ms = 0; ms < 2; ++ms)
                    o[ms][nj] = mfma16(va, pb[ms][kn], o[ms][nj]);
            }
        }
    }

    // reduce row-sums across quads (keys): lanes differing in bits 4,5
#pragma unroll
    for (int ms = 0; ms < 2; ++ms) {
        float v = rs[ms];
        v += __shfl_xor(v, 16, 64);
        v += __shfl_xor(v, 32, 64);
        rs[ms] = v;
    }

    // cross-khalf combine (additive partials). Cb[q][d] stride 65 fp32.
    __syncthreads();                  // all waves done with strips
    float* Cb = (float*)smem;
    if (khalf == 1) {
#pragma unroll
        for (int ms = 0; ms < 2; ++ms) {
            int ql = qhalf * 32 + ms * 16 + l16;
#pragma unroll
            for (int nj = 0; nj < 4; ++nj)
#pragma unroll
                for (int r = 0; r < 4; ++r)
                    Cb[ql * 65 + nj * 16 + quad * 4 + r] = o[ms][nj][r];
        }
        if (lane < 16) {
#pragma unroll
            for (int ms = 0; ms < 2; ++ms)
                Lb[qhalf * 32 + ms * 16 + l16] = rs[ms];
        }
    }
    __syncthreads();
    if (khalf == 0) {
#pragma unroll
        for (int ms = 0; ms < 2; ++ms) {
            int ql = qhalf * 32 + ms * 16 + l16;
            float inv = 1.0f / (rs[ms] + Lb[ql]);
            int q = q0 + ql;
#pragma unroll
            for (int nj = 0; nj < 4; ++nj)
#pragma unroll
                for (int r = 0; r < 4; ++r) {
                    int d = nj * 16 + quad * 4 + r;
                    float v = (o[ms][nj][r] + Cb[ql * 65 + d]) * inv;
                    dd.ctxT[(size_t)(h * 64 + d) * Nq + q] = f32_bf16(v);
                }
        }
    }
}

// ---------------------------------------------------------------------------
// launch — plan as R11 (ws peak 40 MB; d_out u16 staging); dir2 first (LPT).
// ---------------------------------------------------------------------------
extern "C" void kernel_launch(void* const* d_in, const int* in_sizes, int n_in,
                              void* d_out, int out_size, void* d_ws, size_t ws_size,
                              hipStream_t stream) {
    u16* ws = (u16*)d_ws;
    uint32_t* flag = (uint32_t*)ws;
    u16* A = ws + 64;
    const size_t M1 = 1024ull * 1024;

    u16* W8   = A;              // [0,8M)  : 8 weightsT; [0,3M) later ctx1
    u16* Kd1  = A + 8 * M1;     // [8M,10M) : X@WK natural
    u16* VT   = A + 10 * M1;    // [10M,12M): VT[16][64][2048]
    u16* K1d  = A + 12 * M1;    // [12M,15M): X1@WK1 natural
    u16* VT1  = A + 15 * M1;    // [15M,18M): VT1[16][64][3072]
    u16* ctx2 = A + 18 * M1;    // [18M,20M)

    u16* outw = (u16*)d_out;
    u16* Q1s  = outw;           // [0,3M)  X1@WQ1 (bf16 scratch in d_out)
    u16* Qs   = outw + 3 * M1;  // [3M,5M) X@WQ
    u16* Xb   = outw + 5 * M1;  // [5M,7M)  X as bf16
    u16* X1b  = outw + 7 * M1;  // [7M,10M) X1 as bf16

    u16* ctx1 = W8;
    u16* WfcT = W8 + 6 * M1;

    detect_k<<<dim3(1), dim3(256), 0, stream>>>((const u16*)d_in[0], flag);

    XJob xj0 = {d_in[0], Xb,  2048 * 1024};
    XJob xj1 = {d_in[1], X1b, 3072 * 1024};
    convert_x<<<dim3(128, 2), dim3(256), 0, stream>>>(xj0, xj1, flag);

    WBatch8 wb;
    for (int i = 0; i < 8; ++i) { wb.j[i].in = d_in[2 + i]; wb.j[i].out = W8 + (size_t)i * M1; }
    convert_w<<<dim3(16, 16, 8), dim3(256), 0, stream>>>(wb, flag);

    GemmBatch6 gp;
    gp.j[0] = (GemmJob){Xb,  W8,          Qs,  2048, 0, 0, 0};
    gp.j[1] = (GemmJob){Xb,  W8 + M1,     Kd1, 2048, 0, 0, 0};
    gp.j[2] = (GemmJob){Xb,  W8 + 2 * M1, VT,  2048, 0, 0, 2048};
    gp.j[3] = (GemmJob){X1b, W8 + 3 * M1, Q1s, 3072, 0, 0, 0};
    gp.j[4] = (GemmJob){X1b, W8 + 4 * M1, K1d, 3072, 0, 0, 0};
    gp.j[5] = (GemmJob){X1b, W8 + 5 * M1, VT1, 3072, 0, 0, 3072};
    gemm_bt<<<dim3(8, 24, 6), dim3(256), 0, stream>>>(gp, flag);

    // dir2 (48-iter blocks) first — longest-processing-time-first scheduling
    AttnDir a0 = {Qs,  K1d, VT1, ctx2, 2048, 3072, 512};
    AttnDir a1 = {Q1s, Kd1, VT,  ctx1, 3072, 2048, 768};
    attn_k<<<dim3(1280), dim3(256), 0, stream>>>(a0, a1);

    GemmBatch6 gf;
    gf.j[0] = (GemmJob){ctx1, WfcT,      d_out, 3072, 1, 0,               0};
    gf.j[1] = (GemmJob){ctx2, WfcT + M1, d_out, 2048, 1, 3 * 1024 * 1024, 0};
    gf.j[2] = gf.j[0]; gf.j[3] = gf.j[0]; gf.j[4] = gf.j[0]; gf.j[5] = gf.j[0];
    gemm_bt<<<dim3(8, 24, 2), dim3(256), 0, stream>>>(gf, flag);
}

// Round 13
// 290.321 us; speedup vs baseline: 1.0652x; 1.0035x over previous
//
#include <hip/hip_runtime.h>
#include <stdint.h>

typedef unsigned short u16;
typedef unsigned int u32;
typedef u16   u16x4  __attribute__((ext_vector_type(4)));
typedef u16   u16x8  __attribute__((ext_vector_type(8)));
typedef short s16x4  __attribute__((ext_vector_type(4)));
typedef __bf16 bf16x4 __attribute__((ext_vector_type(4)));
typedef __bf16 bf16x8 __attribute__((ext_vector_type(8)));
typedef float f32x4  __attribute__((ext_vector_type(4)));
typedef u32   u32x2  __attribute__((ext_vector_type(2)));
typedef u32   u32x4  __attribute__((ext_vector_type(4)));

typedef __attribute__((address_space(3))) u16 lds_u16;
typedef __attribute__((address_space(1))) const u16 glb_u16;

static __device__ __forceinline__ u16 f32_bf16(float f) {
    uint32_t u = __builtin_bit_cast(uint32_t, f);
    u += 0x7fffu + ((u >> 16) & 1u);          // round-to-nearest-even
    return (u16)(u >> 16);
}
// fast pair-pack: round-half-up + byte-perm (ties-only diff vs RNE)
static __device__ __forceinline__ u32 pack2(float a, float b) {
#if __has_builtin(__builtin_amdgcn_perm)
    u32 ua = __builtin_bit_cast(u32, a) + 0x8000u;
    u32 ub = __builtin_bit_cast(u32, b) + 0x8000u;
    return __builtin_amdgcn_perm(ub, ua, 0x07060302u);   // {ua.hi, ub.hi}
#else
    return (u32)f32_bf16(a) | ((u32)f32_bf16(b) << 16);
#endif
}
#if __has_builtin(__builtin_amdgcn_exp2f)
#define EXP2(x) __builtin_amdgcn_exp2f(x)
#else
#define EXP2(x) __expf((x) * 0.69314718056f)
#endif
static __device__ __forceinline__ u16x8 cvt8(f32x4 a, f32x4 b) {
    u16x8 v;
#pragma unroll
    for (int e = 0; e < 4; ++e) { v[e] = f32_bf16(a[e]); v[4 + e] = f32_bf16(b[e]); }
    return v;
}

// K=16 bf16 MFMA with builtin-name fallback chain (compiled OK in R12)
static __device__ __forceinline__ f32x4 mfma16(u32x2 a, u32x2 b, f32x4 c) {
#if __has_builtin(__builtin_amdgcn_mfma_f32_16x16x16_bf16)
    return __builtin_amdgcn_mfma_f32_16x16x16_bf16(
        __builtin_bit_cast(bf16x4, a), __builtin_bit_cast(bf16x4, b), c, 0, 0, 0);
#elif __has_builtin(__builtin_amdgcn_mfma_f32_16x16x16bf16_1k)
    return __builtin_amdgcn_mfma_f32_16x16x16bf16_1k(
        __builtin_bit_cast(s16x4, a), __builtin_bit_cast(s16x4, b), c, 0, 0, 0);
#else
    f32x4 d;
    asm volatile("v_mfma_f32_16x16x16_bf16 %0, %1, %2, %3"
                 : "=v"(d) : "v"(a), "v"(b), "v"(c));
    return d;
#endif
}

// ---------------------------------------------------------------------------
// 0. dtype detect (verified R5-R12): flag=1 -> fp32 inputs AND fp32 output.
// ---------------------------------------------------------------------------
__global__ __launch_bounds__(256) void detect_k(const u16* __restrict__ X, uint32_t* flag) {
    __shared__ int cnt[256];
    int t = threadIdx.x;
    int c = 0;
#pragma unroll
    for (int i = 0; i < 4; ++i) {
        u16 v = X[t + 256 * i];
        int e = (v >> 7) & 0xFF;
        c += (e >= 0xC2) ? 1 : 0;
    }
    cnt[t] = c;
    __syncthreads();
    for (int s = 128; s > 0; s >>= 1) {
        if (t < s) cnt[t] += cnt[t + s];
        __syncthreads();
    }
    if (t == 0) *flag = (cnt[0] > 32) ? 1u : 0u;
}

// ---------------------------------------------------------------------------
// 0b. X pre-convert to bf16 (identity copy when flag=0).
// ---------------------------------------------------------------------------
struct XJob { const void* in; u16* out; int n; };

__global__ __launch_bounds__(256) void convert_x(XJob j0, XJob j1, const uint32_t* __restrict__ flag) {
    const XJob job = (blockIdx.y == 0) ? j0 : j1;
    const bool f32in = (*flag != 0u);
    const int stride = gridDim.x * 256 * 8;
    for (int i = ((int)blockIdx.x * 256 + (int)threadIdx.x) * 8; i < job.n; i += stride) {
        u16x8 v;
        if (f32in) {
            const float* p = (const float*)job.in + i;
            v = cvt8(*(const f32x4*)p, *(const f32x4*)(p + 4));
        } else {
            v = *(const u16x8*)((const u16*)job.in + i);
        }
        *(u16x8*)(job.out + i) = v;
    }
}

// ---------------------------------------------------------------------------
// 1. Weight convert+transpose, all 8 matrices in one dispatch.
// ---------------------------------------------------------------------------
struct WJob { const void* in; u16* out; };
struct WBatch8 { WJob j[8]; };

__global__ __launch_bounds__(256) void convert_w(WBatch8 args, const uint32_t* __restrict__ flag) {
    __shared__ u16 tile[64][72];
    const bool f32in = (*flag != 0u);
    const void* in = args.j[blockIdx.z].in;
    u16*       out = args.j[blockIdx.z].out;
    const int t  = threadIdx.x;
    const int r0 = blockIdx.y * 64, c0 = blockIdx.x * 64;
    const int lr = t >> 3, lc = (t & 7) * 8;
#pragma unroll
    for (int pass = 0; pass < 2; ++pass) {
        int r = lr + pass * 32;
        u16x8 v;
        if (f32in) {
            const float* p = (const float*)in + (size_t)(r0 + r) * 1024 + c0 + lc;
            v = cvt8(*(const f32x4*)p, *(const f32x4*)(p + 4));
        } else {
            v = *(const u16x8*)((const u16*)in + (size_t)(r0 + r) * 1024 + c0 + lc);
        }
#pragma unroll
        for (int e = 0; e < 8; ++e) tile[r][lc + e] = v[e];
    }
    __syncthreads();
#pragma unroll
    for (int pass = 0; pass < 2; ++pass) {
        int n = lr + pass * 32;
        u16x8 v;
#pragma unroll
        for (int e = 0; e < 8; ++e) v[e] = tile[lc + e][n];
        *(u16x8*)(out + (size_t)(c0 + n) * 1024 + r0 + lc) = v;
    }
}

// ---------------------------------------------------------------------------
// 2. MFMA GEMM, BK=64, global_load_lds staging. cScale: epilogue scale for
//    the bf16 path (folds softmax 1/sqrt(dk)*log2e into Q). VT epilogue now
//    stores PERMUTED key order within each 32-key block: p = g*8+h*4+j
//    (g=key quad, h=key>>4 half, j=low2) so attention PV reads are b128.
// ---------------------------------------------------------------------------
struct GemmJob  { const u16* A; const u16* Bt; void* C; int M; int cF32able; int cOffElems; int vtNk; float cScale; };
struct GemmBatch6 { GemmJob j[6]; };

__global__ __launch_bounds__(256) void gemm_bt(GemmBatch6 b, const uint32_t* __restrict__ flag) {
    const GemmJob job = b.j[blockIdx.z];
    const int K = 1024, N = 1024;
    const int m0 = blockIdx.y * 128;
    if (m0 >= job.M) return;
    const int n0 = blockIdx.x * 128;
    const bool cF = job.cF32able && (*flag != 0u);

    __shared__ u16 As[128 * 64];
    __shared__ u16 Bs[128 * 64];

    const int tid  = threadIdx.x;
    const int lane = tid & 63, wave = tid >> 6;
    const int quad = lane >> 4, l16 = lane & 15;
    const int wrow = wave >> 1, wcol = wave & 1;

    f32x4 acc[4][4];
#pragma unroll
    for (int i = 0; i < 4; ++i)
#pragma unroll
        for (int j = 0; j < 4; ++j) acc[i][j] = (f32x4){0.f, 0.f, 0.f, 0.f};

    for (int k0 = 0; k0 < K; k0 += 64) {
        __syncthreads();
#pragma unroll
        for (int i = 0; i < 4; ++i) {
            int id = tid + 256 * i;
            int row = id >> 3, slot = id & 7;
            int src = (slot ^ (row & 7)) * 8;
            __builtin_amdgcn_global_load_lds(
                (glb_u16*)(job.A + (size_t)(m0 + row) * K + k0 + src),
                (lds_u16*)(As + (size_t)id * 8), 16, 0, 0);
            __builtin_amdgcn_global_load_lds(
                (glb_u16*)(job.Bt + (size_t)(n0 + row) * K + k0 + src),
                (lds_u16*)(Bs + (size_t)id * 8), 16, 0, 0);
        }
        __syncthreads();

#pragma unroll
        for (int kc2 = 0; kc2 < 2; ++kc2) {
            bf16x8 af[4], bfb[4];
#pragma unroll
            for (int i = 0; i < 4; ++i) {
                int r  = wrow * 64 + i * 16 + l16;
                af[i]  = *(const bf16x8*)(As + r * 64 + (((kc2 * 4 + quad) ^ (r & 7)) * 8));
                int rn = wcol * 64 + i * 16 + l16;
                bfb[i] = *(const bf16x8*)(Bs + rn * 64 + (((kc2 * 4 + quad) ^ (rn & 7)) * 8));
            }
#pragma unroll
            for (int i = 0; i < 4; ++i)
#pragma unroll
                for (int j = 0; j < 4; ++j)
                    acc[i][j] = __builtin_amdgcn_mfma_f32_16x16x32_bf16(af[i], bfb[j], acc[i][j], 0, 0, 0);
        }
    }

    if (job.vtNk > 0) {
        u16* VT = (u16*)job.C;
        const int Nk2 = job.vtNk;
#pragma unroll
        for (int i = 0; i < 4; ++i)
#pragma unroll
            for (int j = 0; j < 4; ++j) {
                int n   = n0 + wcol * 64 + j * 16 + l16;
                int hh  = n >> 6, dd = n & 63;
                int key = m0 + wrow * 64 + i * 16 + quad * 4;
                int bq  = key & 31;
                int kp  = (key & ~31) | (((bq >> 2) & 3) * 8 + (bq >> 4) * 4);  // permuted
                u16x4 vv;
#pragma unroll
                for (int r = 0; r < 4; ++r) vv[r] = f32_bf16(acc[i][j][r]);
                *(u16x4*)(VT + (size_t)hh * 64 * Nk2 + (size_t)dd * Nk2 + kp) = vv;
            }
    } else if (cF) {
        float* C = (float*)job.C + job.cOffElems;
#pragma unroll
        for (int i = 0; i < 4; ++i)
#pragma unroll
            for (int j = 0; j < 4; ++j)
#pragma unroll
                for (int r = 0; r < 4; ++r) {
                    int gr = m0 + wrow * 64 + i * 16 + quad * 4 + r;
                    int gc = n0 + wcol * 64 + j * 16 + l16;
                    C[(size_t)gr * N + gc] = acc[i][j][r];
                }
    } else {
        u16* C = (u16*)job.C + job.cOffElems;
        const float cs = job.cScale;
#pragma unroll
        for (int i = 0; i < 4; ++i)
#pragma unroll
            for (int j = 0; j < 4; ++j)
#pragma unroll
                for (int r = 0; r < 4; ++r) {
                    int gr = m0 + wrow * 64 + i * 16 + quad * 4 + r;
                    int gc = n0 + wcol * 64 + j * 16 + l16;
                    C[(size_t)gr * N + gc] = f32_bf16(acc[i][j][r] * cs);
                }
    }
}

// ---------------------------------------------------------------------------
// 3. Fused MFMA attention v7 — transposed-S + exp2 (Q pre-scaled) + perm-VT
//    b128 PV reads + fast pair-pack. Private per-wave K/V strips, barrier-
//    free K-loop, register prefetch. LDS 36.3 KB -> 4 blk/CU. Dir2 first.
// ---------------------------------------------------------------------------
struct AttnDir { const u16* Q; const u16* K; const u16* VT; u16* ctxT; int Nq; int Nk; int nBlk; };

__global__ __launch_bounds__(256, 4) void attn_k(AttnDir d0, AttnDir d1) {
    const int D = 1024;
    int b = blockIdx.x;
    const AttnDir dd = (b < d0.nBlk) ? d0 : d1;
    if (blockIdx.x >= (unsigned)d0.nBlk) b -= d0.nBlk;
    const int h  = b & 15;
    const int q0 = (b >> 4) * 64;
    const int Nq = dd.Nq, Nk = dd.Nk;
    const u16* __restrict__ Qp  = dd.Q;
    const u16* __restrict__ Kp  = dd.K;
    const u16* __restrict__ VTp = dd.VT;

    const int tid  = threadIdx.x;
    const int lane = tid & 63, w = tid >> 6;
    const int quad = lane >> 4, l16 = lane & 15;
    const int qhalf = w & 1, khalf = w >> 1;
    const int halfN = Nk >> 1;

    __shared__ u16 smem[18560];       // 37120 B: 4 x (Ks 2048 + Vs 2560) + Lb
    u16* Ks = smem + w * 4608;        // private [32 keys][64 d], XOR chunks
    u16* Vs = Ks + 2048;              // private [64 d][40] keys PERMUTED order
    float* Lb = (float*)(smem + 18432);

    bf16x8 aq[2][2];                  // pre-scaled Q fragments (B operands)
#pragma unroll
    for (int ms = 0; ms < 2; ++ms)
#pragma unroll
        for (int kc = 0; kc < 2; ++kc) {
            int q = q0 + qhalf * 32 + ms * 16 + l16;
            aq[ms][kc] = *(const bf16x8*)(Qp + (size_t)q * D + h * 64 + kc * 32 + quad * 8);
        }

    f32x4 o[2][4];                    // O^T accumulators [ms][nj]
#pragma unroll
    for (int ms = 0; ms < 2; ++ms)
#pragma unroll
        for (int nj = 0; nj < 4; ++nj) o[ms][nj] = (f32x4){0.f, 0.f, 0.f, 0.f};
    float rs[2] = {0.f, 0.f};         // per-lane (q=l16) partial row-sums
    const size_t vtBase = (size_t)h * 64 * Nk;
    const int gkBase0 = khalf * halfN;

    int krow[4], ksrc[4], vd[4], vc[4];
#pragma unroll
    for (int i = 0; i < 4; ++i) {
        int id = i * 64 + lane;
        krow[i] = id >> 3;
        ksrc[i] = ((id & 7) ^ (krow[i] & 7)) * 8;
        vd[i]   = id >> 2;
        vc[i]   = id & 3;
    }

    u16x8 kr[4], vr[4];
#pragma unroll
    for (int i = 0; i < 4; ++i) {     // prefetch tile 0 (V rows linear copy)
        kr[i] = *(const u16x8*)(Kp + (size_t)(gkBase0 + krow[i]) * D + h * 64 + ksrc[i]);
        vr[i] = *(const u16x8*)(VTp + vtBase + (size_t)vd[i] * Nk + gkBase0 + vc[i] * 8);
    }

    for (int k0 = 0; k0 < halfN; k0 += 32) {
#pragma unroll
        for (int i = 0; i < 4; ++i) {
            *(u16x8*)(Ks + (i * 64 + lane) * 8) = kr[i];
            *(u16x8*)(Vs + vd[i] * 40 + vc[i] * 8) = vr[i];
        }
        {
            int kn = (k0 + 32 < halfN) ? (k0 + 32) : 0;
            int gkb = gkBase0 + kn;
#pragma unroll
            for (int i = 0; i < 4; ++i) {
                kr[i] = *(const u16x8*)(Kp + (size_t)(gkb + krow[i]) * D + h * 64 + ksrc[i]);
                vr[i] = *(const u16x8*)(VTp + vtBase + (size_t)vd[i] * Nk + gkb + vc[i] * 8);
            }
        }

        // S^T = K Q^T
        f32x4 s[2][2];
#pragma unroll
        for (int ms = 0; ms < 2; ++ms)
#pragma unroll
            for (int kn = 0; kn < 2; ++kn) s[ms][kn] = (f32x4){0.f, 0.f, 0.f, 0.f};
#pragma unroll
        for (int kn = 0; kn < 2; ++kn)
#pragma unroll
            for (int kc = 0; kc < 2; ++kc) {
                int keyr = kn * 16 + l16;
                int phys = ((kc * 4 + quad) ^ (keyr & 7)) * 8;
                bf16x8 ak = *(const bf16x8*)(Ks + keyr * 64 + phys);
#pragma unroll
                for (int ms = 0; ms < 2; ++ms)
                    s[ms][kn] = __builtin_amdgcn_mfma_f32_16x16x32_bf16(ak, aq[ms][kc], s[ms][kn], 0, 0, 0);
            }

        // exp2 (Q pre-scaled by 0.125*log2e) + rowsum + pack to B-operand
        u32x2 pb[2][2];
#pragma unroll
        for (int ms = 0; ms < 2; ++ms)
#pragma unroll
            for (int kn = 0; kn < 2; ++kn) {
                float p0 = EXP2(s[ms][kn][0]);
                float p1 = EXP2(s[ms][kn][1]);
                float p2 = EXP2(s[ms][kn][2]);
                float p3 = EXP2(s[ms][kn][3]);
                rs[ms] += (p0 + p1) + (p2 + p3);
                pb[ms][kn][0] = pack2(p0, p1);
                pb[ms][kn][1] = pack2(p2, p3);
            }

        // PV: one b128 per nj serves both kn halves (permuted Vs order)
#pragma unroll
        for (int nj = 0; nj < 4; ++nj) {
            int d = nj * 16 + l16;
            u32x4 va = *(const u32x4*)(Vs + d * 40 + quad * 8);
            u32x2 va0 = {va[0], va[1]}, va1 = {va[2], va[3]};
#pragma unroll
            for (int ms = 0; ms < 2; ++ms) {
                o[ms][nj] = mfma16(va0, pb[ms][0], o[ms][nj]);
                o[ms][nj] = mfma16(va1, pb[ms][1], o[ms][nj]);
            }
        }
    }

    // reduce row-sums across quads (keys)
#pragma unroll
    for (int ms = 0; ms < 2; ++ms) {
        float v = rs[ms];
        v += __shfl_xor(v, 16, 64);
        v += __shfl_xor(v, 32, 64);
        rs[ms] = v;
    }

    // cross-khalf combine (additive partials). Cb[q][d] stride 65 fp32.
    __syncthreads();
    float* Cb = (float*)smem;
    if (khalf == 1) {
#pragma unroll
        for (int ms = 0; ms < 2; ++ms) {
            int ql = qhalf * 32 + ms * 16 + l16;
#pragma unroll
            for (int nj = 0; nj < 4; ++nj)
#pragma unroll
                for (int r = 0; r < 4; ++r)
                    Cb[ql * 65 + nj * 16 + quad * 4 + r] = o[ms][nj][r];
        }
        if (lane < 16) {
#pragma unroll
            for (int ms = 0; ms < 2; ++ms)
                Lb[qhalf * 32 + ms * 16 + l16] = rs[ms];
        }
    }
    __syncthreads();
    if (khalf == 0) {
#pragma unroll
        for (int ms = 0; ms < 2; ++ms) {
            int ql = qhalf * 32 + ms * 16 + l16;
            float inv = 1.0f / (rs[ms] + Lb[ql]);
            int q = q0 + ql;
#pragma unroll
            for (int nj = 0; nj < 4; ++nj)
#pragma unroll
                for (int r = 0; r < 4; ++r) {
                    int d = nj * 16 + quad * 4 + r;
                    float v = (o[ms][nj][r] + Cb[ql * 65 + d]) * inv;
                    dd.ctxT[(size_t)(h * 64 + d) * Nq + q] = f32_bf16(v);
                }
        }
    }
}

// ---------------------------------------------------------------------------
// launch — plan as R12 (ws peak 40 MB; d_out u16 staging); dir2 first (LPT).
// Q-projections pre-scaled by 0.125*log2(e) for the exp2 softmax.
// ---------------------------------------------------------------------------
extern "C" void kernel_launch(void* const* d_in, const int* in_sizes, int n_in,
                              void* d_out, int out_size, void* d_ws, size_t ws_size,
                              hipStream_t stream) {
    u16* ws = (u16*)d_ws;
    uint32_t* flag = (uint32_t*)ws;
    u16* A = ws + 64;
    const size_t M1 = 1024ull * 1024;
    const float QSC = 0.125f * 1.44269504089f;   // 1/sqrt(dk) * log2(e)

    u16* W8   = A;              // [0,8M)  : 8 weightsT; [0,3M) later ctx1
    u16* Kd1  = A + 8 * M1;     // [8M,10M) : X@WK natural
    u16* VT   = A + 10 * M1;    // [10M,12M): VT[16][64][2048] (permuted keys)
    u16* K1d  = A + 12 * M1;    // [12M,15M): X1@WK1 natural
    u16* VT1  = A + 15 * M1;    // [15M,18M): VT1[16][64][3072] (permuted keys)
    u16* ctx2 = A + 18 * M1;    // [18M,20M)

    u16* outw = (u16*)d_out;
    u16* Q1s  = outw;           // [0,3M)  X1@WQ1 (bf16 scratch in d_out)
    u16* Qs   = outw + 3 * M1;  // [3M,5M) X@WQ
    u16* Xb   = outw + 5 * M1;  // [5M,7M)  X as bf16
    u16* X1b  = outw + 7 * M1;  // [7M,10M) X1 as bf16

    u16* ctx1 = W8;
    u16* WfcT = W8 + 6 * M1;

    detect_k<<<dim3(1), dim3(256), 0, stream>>>((const u16*)d_in[0], flag);

    XJob xj0 = {d_in[0], Xb,  2048 * 1024};
    XJob xj1 = {d_in[1], X1b, 3072 * 1024};
    convert_x<<<dim3(128, 2), dim3(256), 0, stream>>>(xj0, xj1, flag);

    WBatch8 wb;
    for (int i = 0; i < 8; ++i) { wb.j[i].in = d_in[2 + i]; wb.j[i].out = W8 + (size_t)i * M1; }
    convert_w<<<dim3(16, 16, 8), dim3(256), 0, stream>>>(wb, flag);

    GemmBatch6 gp;
    gp.j[0] = (GemmJob){Xb,  W8,          Qs,  2048, 0, 0, 0,    QSC};
    gp.j[1] = (GemmJob){Xb,  W8 + M1,     Kd1, 2048, 0, 0, 0,    1.0f};
    gp.j[2] = (GemmJob){Xb,  W8 + 2 * M1, VT,  2048, 0, 0, 2048, 1.0f};
    gp.j[3] = (GemmJob){X1b, W8 + 3 * M1, Q1s, 3072, 0, 0, 0,    QSC};
    gp.j[4] = (GemmJob){X1b, W8 + 4 * M1, K1d, 3072, 0, 0, 0,    1.0f};
    gp.j[5] = (GemmJob){X1b, W8 + 5 * M1, VT1, 3072, 0, 0, 3072, 1.0f};
    gemm_bt<<<dim3(8, 24, 6), dim3(256), 0, stream>>>(gp, flag);

    // dir2 (48-iter blocks) first — longest-processing-time-first
    AttnDir a0 = {Qs,  K1d, VT1, ctx2, 2048, 3072, 512};
    AttnDir a1 = {Q1s, Kd1, VT,  ctx1, 3072, 2048, 768};
    attn_k<<<dim3(1280), dim3(256), 0, stream>>>(a0, a1);

    GemmBatch6 gf;
    gf.j[0] = (GemmJob){ctx1, WfcT,      d_out, 3072, 1, 0,               0, 1.0f};
    gf.j[1] = (GemmJob){ctx2, WfcT + M1, d_out, 2048, 1, 3 * 1024 * 1024, 0, 1.0f};
    gf.j[2] = gf.j[0]; gf.j[3] = gf.j[0]; gf.j[4] = gf.j[0]; gf.j[5] = gf.j[0];
    gemm_bt<<<dim3(8, 24, 2), dim3(256), 0, stream>>>(gf, flag);
}

// Round 14
// 286.337 us; speedup vs baseline: 1.0800x; 1.0139x over previous
//
#include <hip/hip_runtime.h>
#include <stdint.h>

typedef unsigned short u16;
typedef unsigned int u32;
typedef u16   u16x4  __attribute__((ext_vector_type(4)));
typedef u16   u16x8  __attribute__((ext_vector_type(8)));
typedef __bf16 bf16x8 __attribute__((ext_vector_type(8)));
typedef float f32x4  __attribute__((ext_vector_type(4)));
typedef u32   u32x2  __attribute__((ext_vector_type(2)));
typedef u32   u32x4  __attribute__((ext_vector_type(4)));

typedef __attribute__((address_space(3))) u16 lds_u16;
typedef __attribute__((address_space(1))) const u16 glb_u16;

static __device__ __forceinline__ u16 f32_bf16(float f) {
    uint32_t u = __builtin_bit_cast(uint32_t, f);
    u += 0x7fffu + ((u >> 16) & 1u);          // round-to-nearest-even
    return (u16)(u >> 16);
}
// fast pair-pack: round-half-up + byte-perm (ties-only diff vs RNE)
static __device__ __forceinline__ u32 pack2(float a, float b) {
#if __has_builtin(__builtin_amdgcn_perm)
    u32 ua = __builtin_bit_cast(u32, a) + 0x8000u;
    u32 ub = __builtin_bit_cast(u32, b) + 0x8000u;
    return __builtin_amdgcn_perm(ub, ua, 0x07060302u);   // {ua.hi, ub.hi}
#else
    return (u32)f32_bf16(a) | ((u32)f32_bf16(b) << 16);
#endif
}
#if __has_builtin(__builtin_amdgcn_exp2f)
#define EXP2(x) __builtin_amdgcn_exp2f(x)
#else
#define EXP2(x) __expf((x) * 0.69314718056f)
#endif
static __device__ __forceinline__ u16x8 cvt8(f32x4 a, f32x4 b) {
    u16x8 v;
#pragma unroll
    for (int e = 0; e < 4; ++e) { v[e] = f32_bf16(a[e]); v[4 + e] = f32_bf16(b[e]); }
    return v;
}

// ---------------------------------------------------------------------------
// 0. dtype detect (verified R5-R13): flag=1 -> fp32 inputs AND fp32 output.
// ---------------------------------------------------------------------------
__global__ __launch_bounds__(256) void detect_k(const u16* __restrict__ X, uint32_t* flag) {
    __shared__ int cnt[256];
    int t = threadIdx.x;
    int c = 0;
#pragma unroll
    for (int i = 0; i < 4; ++i) {
        u16 v = X[t + 256 * i];
        int e = (v >> 7) & 0xFF;
        c += (e >= 0xC2) ? 1 : 0;
    }
    cnt[t] = c;
    __syncthreads();
    for (int s = 128; s > 0; s >>= 1) {
        if (t < s) cnt[t] += cnt[t + s];
        __syncthreads();
    }
    if (t == 0) *flag = (cnt[0] > 32) ? 1u : 0u;
}

// ---------------------------------------------------------------------------
// 0b. X pre-convert to bf16 (identity copy when flag=0).
// ---------------------------------------------------------------------------
struct XJob { const void* in; u16* out; int n; };

__global__ __launch_bounds__(256) void convert_x(XJob j0, XJob j1, const uint32_t* __restrict__ flag) {
    const XJob job = (blockIdx.y == 0) ? j0 : j1;
    const bool f32in = (*flag != 0u);
    const int stride = gridDim.x * 256 * 8;
    for (int i = ((int)blockIdx.x * 256 + (int)threadIdx.x) * 8; i < job.n; i += stride) {
        u16x8 v;
        if (f32in) {
            const float* p = (const float*)job.in + i;
            v = cvt8(*(const f32x4*)p, *(const f32x4*)(p + 4));
        } else {
            v = *(const u16x8*)((const u16*)job.in + i);
        }
        *(u16x8*)(job.out + i) = v;
    }
}

// ---------------------------------------------------------------------------
// 1. Weight convert+transpose, all 8 matrices in one dispatch.
// ---------------------------------------------------------------------------
struct WJob { const void* in; u16* out; };
struct WBatch8 { WJob j[8]; };

__global__ __launch_bounds__(256) void convert_w(WBatch8 args, const uint32_t* __restrict__ flag) {
    __shared__ u16 tile[64][72];
    const bool f32in = (*flag != 0u);
    const void* in = args.j[blockIdx.z].in;
    u16*       out = args.j[blockIdx.z].out;
    const int t  = threadIdx.x;
    const int r0 = blockIdx.y * 64, c0 = blockIdx.x * 64;
    const int lr = t >> 3, lc = (t & 7) * 8;
#pragma unroll
    for (int pass = 0; pass < 2; ++pass) {
        int r = lr + pass * 32;
        u16x8 v;
        if (f32in) {
            const float* p = (const float*)in + (size_t)(r0 + r) * 1024 + c0 + lc;
            v = cvt8(*(const f32x4*)p, *(const f32x4*)(p + 4));
        } else {
            v = *(const u16x8*)((const u16*)in + (size_t)(r0 + r) * 1024 + c0 + lc);
        }
#pragma unroll
        for (int e = 0; e < 8; ++e) tile[r][lc + e] = v[e];
    }
    __syncthreads();
#pragma unroll
    for (int pass = 0; pass < 2; ++pass) {
        int n = lr + pass * 32;
        u16x8 v;
#pragma unroll
        for (int e = 0; e < 8; ++e) v[e] = tile[lc + e][n];
        *(u16x8*)(out + (size_t)(c0 + n) * 1024 + r0 + lc) = v;
    }
}

// ---------------------------------------------------------------------------
// 2. MFMA GEMM, BK=64, global_load_lds staging. GRID SWIZZLE: blockIdx.x =
//    m-tile (bid%8 = m%8 -> each XCD owns 3 m-tiles; per-XCD working set
//    A 768KB + B 2MB < 4MB L2). VT epilogue: permuted key order (R13).
// ---------------------------------------------------------------------------
struct GemmJob  { const u16* A; const u16* Bt; void* C; int M; int cF32able; int cOffElems; int vtNk; float cScale; };
struct GemmBatch6 { GemmJob j[6]; };

__global__ __launch_bounds__(256) void gemm_bt(GemmBatch6 b, const uint32_t* __restrict__ flag) {
    const GemmJob job = b.j[blockIdx.z];
    const int K = 1024, N = 1024;
    const int m0 = blockIdx.x * 128;           // x = m-tile (XCD locality)
    if (m0 >= job.M) return;
    const int n0 = blockIdx.y * 128;
    const bool cF = job.cF32able && (*flag != 0u);

    __shared__ u16 As[128 * 64];
    __shared__ u16 Bs[128 * 64];

    const int tid  = threadIdx.x;
    const int lane = tid & 63, wave = tid >> 6;
    const int quad = lane >> 4, l16 = lane & 15;
    const int wrow = wave >> 1, wcol = wave & 1;

    f32x4 acc[4][4];
#pragma unroll
    for (int i = 0; i < 4; ++i)
#pragma unroll
        for (int j = 0; j < 4; ++j) acc[i][j] = (f32x4){0.f, 0.f, 0.f, 0.f};

    for (int k0 = 0; k0 < K; k0 += 64) {
        __syncthreads();
#pragma unroll
        for (int i = 0; i < 4; ++i) {
            int id = tid + 256 * i;
            int row = id >> 3, slot = id & 7;
            int src = (slot ^ (row & 7)) * 8;
            __builtin_amdgcn_global_load_lds(
                (glb_u16*)(job.A + (size_t)(m0 + row) * K + k0 + src),
                (lds_u16*)(As + (size_t)id * 8), 16, 0, 0);
            __builtin_amdgcn_global_load_lds(
                (glb_u16*)(job.Bt + (size_t)(n0 + row) * K + k0 + src),
                (lds_u16*)(Bs + (size_t)id * 8), 16, 0, 0);
        }
        __syncthreads();

#pragma unroll
        for (int kc2 = 0; kc2 < 2; ++kc2) {
            bf16x8 af[4], bfb[4];
#pragma unroll
            for (int i = 0; i < 4; ++i) {
                int r  = wrow * 64 + i * 16 + l16;
                af[i]  = *(const bf16x8*)(As + r * 64 + (((kc2 * 4 + quad) ^ (r & 7)) * 8));
                int rn = wcol * 64 + i * 16 + l16;
                bfb[i] = *(const bf16x8*)(Bs + rn * 64 + (((kc2 * 4 + quad) ^ (rn & 7)) * 8));
            }
#pragma unroll
            for (int i = 0; i < 4; ++i)
#pragma unroll
                for (int j = 0; j < 4; ++j)
                    acc[i][j] = __builtin_amdgcn_mfma_f32_16x16x32_bf16(af[i], bfb[j], acc[i][j], 0, 0, 0);
        }
    }

    if (job.vtNk > 0) {
        u16* VT = (u16*)job.C;
        const int Nk2 = job.vtNk;
#pragma unroll
        for (int i = 0; i < 4; ++i)
#pragma unroll
            for (int j = 0; j < 4; ++j) {
                int n   = n0 + wcol * 64 + j * 16 + l16;
                int hh  = n >> 6, dd = n & 63;
                int key = m0 + wrow * 64 + i * 16 + quad * 4;
                int bq  = key & 31;
                int kp  = (key & ~31) | (((bq >> 2) & 3) * 8 + (bq >> 4) * 4);  // permuted
                u16x4 vv;
#pragma unroll
                for (int r = 0; r < 4; ++r) vv[r] = f32_bf16(acc[i][j][r]);
                *(u16x4*)(VT + (size_t)hh * 64 * Nk2 + (size_t)dd * Nk2 + kp) = vv;
            }
    } else if (cF) {
        float* C = (float*)job.C + job.cOffElems;
#pragma unroll
        for (int i = 0; i < 4; ++i)
#pragma unroll
            for (int j = 0; j < 4; ++j)
#pragma unroll
                for (int r = 0; r < 4; ++r) {
                    int gr = m0 + wrow * 64 + i * 16 + quad * 4 + r;
                    int gc = n0 + wcol * 64 + j * 16 + l16;
                    C[(size_t)gr * N + gc] = acc[i][j][r];
                }
    } else {
        u16* C = (u16*)job.C + job.cOffElems;
        const float cs = job.cScale;
#pragma unroll
        for (int i = 0; i < 4; ++i)
#pragma unroll
            for (int j = 0; j < 4; ++j)
#pragma unroll
                for (int r = 0; r < 4; ++r) {
                    int gr = m0 + wrow * 64 + i * 16 + quad * 4 + r;
                    int gc = n0 + wcol * 64 + j * 16 + l16;
                    C[(size_t)gr * N + gc] = f32_bf16(acc[i][j][r] * cs);
                }
    }
}

// ---------------------------------------------------------------------------
// 3. Fused MFMA attention v8 — PV now a single mfma 16x16x32 per (ms,nj):
//    permuted-VT b128 read IS the A-operand (k=quad*8+j over both kn halves),
//    and the 4 packed P words concatenate to exactly its B-operand. Halves
//    PV MFMA count vs v7. Private strips, barrier-free loop, reg prefetch.
// ---------------------------------------------------------------------------
struct AttnDir { const u16* Q; const u16* K; const u16* VT; u16* ctxT; int Nq; int Nk; int nBlk; };

__global__ __launch_bounds__(256, 4) void attn_k(AttnDir d0, AttnDir d1) {
    const int D = 1024;
    int b = blockIdx.x;
    const AttnDir dd = (b < d0.nBlk) ? d0 : d1;
    if (blockIdx.x >= (unsigned)d0.nBlk) b -= d0.nBlk;
    const int h  = b & 15;
    const int q0 = (b >> 4) * 64;
    const int Nq = dd.Nq, Nk = dd.Nk;
    const u16* __restrict__ Qp  = dd.Q;
    const u16* __restrict__ Kp  = dd.K;
    const u16* __restrict__ VTp = dd.VT;

    const int tid  = threadIdx.x;
    const int lane = tid & 63, w = tid >> 6;
    const int quad = lane >> 4, l16 = lane & 15;
    const int qhalf = w & 1, khalf = w >> 1;
    const int halfN = Nk >> 1;

    __shared__ u16 smem[18560];       // 37120 B: 4 x (Ks 2048 + Vs 2560) + Lb
    u16* Ks = smem + w * 4608;        // private [32 keys][64 d], XOR chunks
    u16* Vs = Ks + 2048;              // private [64 d][40] keys PERMUTED order
    float* Lb = (float*)(smem + 18432);

    bf16x8 aq[2][2];                  // pre-scaled Q fragments (B operands)
#pragma unroll
    for (int ms = 0; ms < 2; ++ms)
#pragma unroll
        for (int kc = 0; kc < 2; ++kc) {
            int q = q0 + qhalf * 32 + ms * 16 + l16;
            aq[ms][kc] = *(const bf16x8*)(Qp + (size_t)q * D + h * 64 + kc * 32 + quad * 8);
        }

    f32x4 o[2][4];                    // O^T accumulators [ms][nj]
#pragma unroll
    for (int ms = 0; ms < 2; ++ms)
#pragma unroll
        for (int nj = 0; nj < 4; ++nj) o[ms][nj] = (f32x4){0.f, 0.f, 0.f, 0.f};
    float rs[2] = {0.f, 0.f};         // per-lane (q=l16) partial row-sums
    const size_t vtBase = (size_t)h * 64 * Nk;
    const int gkBase0 = khalf * halfN;

    int krow[4], ksrc[4], vd[4], vc[4];
#pragma unroll
    for (int i = 0; i < 4; ++i) {
        int id = i * 64 + lane;
        krow[i] = id >> 3;
        ksrc[i] = ((id & 7) ^ (krow[i] & 7)) * 8;
        vd[i]   = id >> 2;
        vc[i]   = id & 3;
    }

    u16x8 kr[4], vr[4];
#pragma unroll
    for (int i = 0; i < 4; ++i) {     // prefetch tile 0 (V rows linear copy)
        kr[i] = *(const u16x8*)(Kp + (size_t)(gkBase0 + krow[i]) * D + h * 64 + ksrc[i]);
        vr[i] = *(const u16x8*)(VTp + vtBase + (size_t)vd[i] * Nk + gkBase0 + vc[i] * 8);
    }

    for (int k0 = 0; k0 < halfN; k0 += 32) {
#pragma unroll
        for (int i = 0; i < 4; ++i) {
            *(u16x8*)(Ks + (i * 64 + lane) * 8) = kr[i];
            *(u16x8*)(Vs + vd[i] * 40 + vc[i] * 8) = vr[i];
        }
        {
            int kn = (k0 + 32 < halfN) ? (k0 + 32) : 0;
            int gkb = gkBase0 + kn;
#pragma unroll
            for (int i = 0; i < 4; ++i) {
                kr[i] = *(const u16x8*)(Kp + (size_t)(gkb + krow[i]) * D + h * 64 + ksrc[i]);
                vr[i] = *(const u16x8*)(VTp + vtBase + (size_t)vd[i] * Nk + gkb + vc[i] * 8);
            }
        }

        // S^T = K Q^T
        f32x4 s[2][2];
#pragma unroll
        for (int ms = 0; ms < 2; ++ms)
#pragma unroll
            for (int kn = 0; kn < 2; ++kn) s[ms][kn] = (f32x4){0.f, 0.f, 0.f, 0.f};
#pragma unroll
        for (int kn = 0; kn < 2; ++kn)
#pragma unroll
            for (int kc = 0; kc < 2; ++kc) {
                int keyr = kn * 16 + l16;
                int phys = ((kc * 4 + quad) ^ (keyr & 7)) * 8;
                bf16x8 ak = *(const bf16x8*)(Ks + keyr * 64 + phys);
#pragma unroll
                for (int ms = 0; ms < 2; ++ms)
                    s[ms][kn] = __builtin_amdgcn_mfma_f32_16x16x32_bf16(ak, aq[ms][kc], s[ms][kn], 0, 0, 0);
            }

        // exp2 (Q pre-scaled) + rowsum + pack P as a full mfma32 B-operand:
        // B k-order = quad*8+j: j 0..3 -> kn0 keys quad*4+j, j 4..7 -> kn1
        // (matches the permuted-VT key order of the va read below).
        u32x4 pbf[2];
#pragma unroll
        for (int ms = 0; ms < 2; ++ms) {
#pragma unroll
            for (int kn = 0; kn < 2; ++kn) {
                float p0 = EXP2(s[ms][kn][0]);
                float p1 = EXP2(s[ms][kn][1]);
                float p2 = EXP2(s[ms][kn][2]);
                float p3 = EXP2(s[ms][kn][3]);
                rs[ms] += (p0 + p1) + (p2 + p3);
                pbf[ms][kn * 2 + 0] = pack2(p0, p1);
                pbf[ms][kn * 2 + 1] = pack2(p2, p3);
            }
        }

        // PV: one b128 V read + ONE mfma32 per (nj, ms)
#pragma unroll
        for (int nj = 0; nj < 4; ++nj) {
            int d = nj * 16 + l16;
            bf16x8 va = *(const bf16x8*)(Vs + d * 40 + quad * 8);
#pragma unroll
            for (int ms = 0; ms < 2; ++ms)
                o[ms][nj] = __builtin_amdgcn_mfma_f32_16x16x32_bf16(
                    va, __builtin_bit_cast(bf16x8, pbf[ms]), o[ms][nj], 0, 0, 0);
        }
    }

    // reduce row-sums across quads (keys)
#pragma unroll
    for (int ms = 0; ms < 2; ++ms) {
        float v = rs[ms];
        v += __shfl_xor(v, 16, 64);
        v += __shfl_xor(v, 32, 64);
        rs[ms] = v;
    }

    // cross-khalf combine (additive partials). Cb[q][d] stride 65 fp32.
    __syncthreads();
    float* Cb = (float*)smem;
    if (khalf == 1) {
#pragma unroll
        for (int ms = 0; ms < 2; ++ms) {
            int ql = qhalf * 32 + ms * 16 + l16;
#pragma unroll
            for (int nj = 0; nj < 4; ++nj)
#pragma unroll
                for (int r = 0; r < 4; ++r)
                    Cb[ql * 65 + nj * 16 + quad * 4 + r] = o[ms][nj][r];
        }
        if (lane < 16) {
#pragma unroll
            for (int ms = 0; ms < 2; ++ms)
                Lb[qhalf * 32 + ms * 16 + l16] = rs[ms];
        }
    }
    __syncthreads();
    if (khalf == 0) {
#pragma unroll
        for (int ms = 0; ms < 2; ++ms) {
            int ql = qhalf * 32 + ms * 16 + l16;
            float inv = 1.0f / (rs[ms] + Lb[ql]);
            int q = q0 + ql;
#pragma unroll
            for (int nj = 0; nj < 4; ++nj)
#pragma unroll
                for (int r = 0; r < 4; ++r) {
                    int d = nj * 16 + quad * 4 + r;
                    float v = (o[ms][nj][r] + Cb[ql * 65 + d]) * inv;
                    dd.ctxT[(size_t)(h * 64 + d) * Nq + q] = f32_bf16(v);
                }
        }
    }
}

// ---------------------------------------------------------------------------
// launch — plan as R13 (ws peak 40 MB; d_out u16 staging); dir2 first (LPT).
// GEMM grids now (m-tiles, n-tiles, jobs) for the XCD swizzle.
// ---------------------------------------------------------------------------
extern "C" void kernel_launch(void* const* d_in, const int* in_sizes, int n_in,
                              void* d_out, int out_size, void* d_ws, size_t ws_size,
                              hipStream_t stream) {
    u16* ws = (u16*)d_ws;
    uint32_t* flag = (uint32_t*)ws;
    u16* A = ws + 64;
    const size_t M1 = 1024ull * 1024;
    const float QSC = 0.125f * 1.44269504089f;   // 1/sqrt(dk) * log2(e)

    u16* W8   = A;              // [0,8M)  : 8 weightsT; [0,3M) later ctx1
    u16* Kd1  = A + 8 * M1;     // [8M,10M) : X@WK natural
    u16* VT   = A + 10 * M1;    // [10M,12M): VT[16][64][2048] (permuted keys)
    u16* K1d  = A + 12 * M1;    // [12M,15M): X1@WK1 natural
    u16* VT1  = A + 15 * M1;    // [15M,18M): VT1[16][64][3072] (permuted keys)
    u16* ctx2 = A + 18 * M1;    // [18M,20M)

    u16* outw = (u16*)d_out;
    u16* Q1s  = outw;           // [0,3M)  X1@WQ1 (bf16 scratch in d_out)
    u16* Qs   = outw + 3 * M1;  // [3M,5M) X@WQ
    u16* Xb   = outw + 5 * M1;  // [5M,7M)  X as bf16
    u16* X1b  = outw + 7 * M1;  // [7M,10M) X1 as bf16

    u16* ctx1 = W8;
    u16* WfcT = W8 + 6 * M1;

    detect_k<<<dim3(1), dim3(256), 0, stream>>>((const u16*)d_in[0], flag);

    XJob xj0 = {d_in[0], Xb,  2048 * 1024};
    XJob xj1 = {d_in[1], X1b, 3072 * 1024};
    convert_x<<<dim3(128, 2), dim3(256), 0, stream>>>(xj0, xj1, flag);

    WBatch8 wb;
    for (int i = 0; i < 8; ++i) { wb.j[i].in = d_in[2 + i]; wb.j[i].out = W8 + (size_t)i * M1; }
    convert_w<<<dim3(16, 16, 8), dim3(256), 0, stream>>>(wb, flag);

    GemmBatch6 gp;
    gp.j[0] = (GemmJob){Xb,  W8,          Qs,  2048, 0, 0, 0,    QSC};
    gp.j[1] = (GemmJob){Xb,  W8 + M1,     Kd1, 2048, 0, 0, 0,    1.0f};
    gp.j[2] = (GemmJob){Xb,  W8 + 2 * M1, VT,  2048, 0, 0, 2048, 1.0f};
    gp.j[3] = (GemmJob){X1b, W8 + 3 * M1, Q1s, 3072, 0, 0, 0,    QSC};
    gp.j[4] = (GemmJob){X1b, W8 + 4 * M1, K1d, 3072, 0, 0, 0,    1.0f};
    gp.j[5] = (GemmJob){X1b, W8 + 5 * M1, VT1, 3072, 0, 0, 3072, 1.0f};
    gemm_bt<<<dim3(24, 8, 6), dim3(256), 0, stream>>>(gp, flag);   // x=m-tiles

    // dir2 (48-iter blocks) first — longest-processing-time-first
    AttnDir a0 = {Qs,  K1d, VT1, ctx2, 2048, 3072, 512};
    AttnDir a1 = {Q1s, Kd1, VT,  ctx1, 3072, 2048, 768};
    attn_k<<<dim3(1280), dim3(256), 0, stream>>>(a0, a1);

    GemmBatch6 gf;
    gf.j[0] = (GemmJob){ctx1, WfcT,      d_out, 3072, 1, 0,               0, 1.0f};
    gf.j[1] = (GemmJob){ctx2, WfcT + M1, d_out, 2048, 1, 3 * 1024 * 1024, 0, 1.0f};
    gf.j[2] = gf.j[0]; gf.j[3] = gf.j[0]; gf.j[4] = gf.j[0]; gf.j[5] = gf.j[0];
    gemm_bt<<<dim3(24, 8, 2), dim3(256), 0, stream>>>(gf, flag);   // x=m-tiles
}